// Round 8
// baseline (232.364 us; speedup 1.0000x reference)
//
#include <hip/hip_runtime.h>
#include <hip/hip_bf16.h>
#include <cstdint>
#include <cstddef>

// Problem constants
#define NT 8192
#define DD 512
#define HH 2048
#define NE 4
// ffn1: BM=288,BN=256,BK=64, 2-slot dbuf (139 KB, 1 blk/CU), 2-phase per-m-streamed, chunk-counted vmcnt.
//       <=60 m-tiles x 8 n-tiles <= 480 blocks -> TWO rounds guaranteed.
#define ASZ1  18432    // A slot shorts: 288x64
#define SLOT1 34816    // + B 256x64 (16384)
// ffn2: BM=160,BN=128,BK=64, 2-slot dbuf (72 KB, 2 blk/CU), ~416 blocks ALL co-resident
#define SLOT2 18432    // shorts: A 160x64 (10240) + B 128x64 (8192)
#define ASZ2  10240
#define RP1 264        // ffn1 repack row stride (shorts)
#define RP2 136        // ffn2 repack row stride (shorts)
#define FFN1_GRID 512  // 8 mt-groups x 8 xcd x 8 n-tiles (capacity 64 m-tiles of 288; worst case 60)
#define FFN2_GRID 448  // 14 mt-groups x 8 xcd x 4 n-tiles

typedef short short8 __attribute__((ext_vector_type(8)));
typedef float floatx4 __attribute__((ext_vector_type(4)));

static __device__ __forceinline__ unsigned short f2bf(float f) {
    union { float f; uint32_t u; } v; v.f = f;
    uint32_t u = v.u;
    u += 0x7FFFu + ((u >> 16) & 1u);   // round-to-nearest-even
    return (unsigned short)(u >> 16);
}
static __device__ __forceinline__ float bf2f(unsigned short u) {
    union { uint32_t u; float f; } v; v.u = ((uint32_t)u) << 16; return v.f;
}

// async global->LDS, 16B per lane. LDS dest = wave-uniform base + lane*16 (addresses below are lane-linear).
static __device__ __forceinline__ void gld_lds16(const unsigned short* g, unsigned short* l) {
    __builtin_amdgcn_global_load_lds(
        (const __attribute__((address_space(1))) void*)g,
        (__attribute__((address_space(3))) void*)l, 16, 0, 0);
}

// ------------- merged prep (512 thr): weight transpose+cast (blocks 0..2047) + gate (2048..) -------------
__global__ __launch_bounds__(512) void k_prep(
    const float* __restrict__ w1, unsigned short* __restrict__ w1t,
    const float* __restrict__ w2, unsigned short* __restrict__ w2t,
    const float* __restrict__ h, const float* __restrict__ wg,
    int* __restrict__ sel, float* __restrict__ gv, unsigned short* __restrict__ hb) {
    int t = threadIdx.x;
    if (blockIdx.x < 2048) {
        int z = blockIdx.x >> 8;            // 256 blocks per expert-matrix
        int rem = blockIdx.x & 255;
        const float* in; unsigned short* out; int R, C, by, bx;
        if (z < 4) {
            in = w1 + (size_t)z * DD * HH; out = w1t + (size_t)z * DD * HH;
            R = DD; C = HH; by = rem >> 5; bx = rem & 31;      // 8 x 32 tiles
        } else {
            in = w2 + (size_t)(z - 4) * HH * DD; out = w2t + (size_t)(z - 4) * HH * DD;
            R = HH; C = DD; by = rem >> 3; bx = rem & 7;       // 32 x 8 tiles
        }
        int r0 = by * 64, c0 = bx * 64;
        __shared__ float tl[64 * 65];       // tl[c*65 + r] (col-major, S=65 -> conflict-free)
        int rr = t >> 4, c4 = (t & 15) * 4;
#pragma unroll
        for (int p = 0; p < 2; p++) {
            int r = rr + p * 32;
            float4 v = *(const float4*)(in + (size_t)(r0 + r) * C + c0 + c4);
            tl[(c4 + 0) * 65 + r] = v.x;
            tl[(c4 + 1) * 65 + r] = v.y;
            tl[(c4 + 2) * 65 + r] = v.z;
            tl[(c4 + 3) * 65 + r] = v.w;
        }
        __syncthreads();
        int c = t >> 3, seg = t & 7;
        unsigned short tmp[8];
#pragma unroll
        for (int k = 0; k < 8; k++) tmp[k] = f2bf(tl[c * 65 + seg * 8 + k]);
        *(uint4*)(out + (size_t)(c0 + c) * R + r0 + seg * 8) = *(const uint4*)tmp;
        return;
    }
    // ---- gating: fp32 logits, exact top-2, softmax over top-2, fused h->bf16 cast (8 tokens/block) ----
    int wid = t >> 6, lane = t & 63;
    int n = (blockIdx.x - 2048) * 8 + wid;
    const float* hr = h + (size_t)n * DD;
    int d0 = lane * 8;
    float hv[8];
    *(float4*)(hv)     = *(const float4*)(hr + d0);
    *(float4*)(hv + 4) = *(const float4*)(hr + d0 + 4);
    unsigned short tmp[8];
#pragma unroll
    for (int j = 0; j < 8; j++) tmp[j] = f2bf(hv[j]);
    *(uint4*)(hb + (size_t)n * DD + d0) = *(const uint4*)tmp;

    float a0 = 0.f, a1 = 0.f, a2 = 0.f, a3 = 0.f;
#pragma unroll
    for (int j = 0; j < 8; j++) {
        float4 w = *(const float4*)(wg + (size_t)(d0 + j) * 4);
        a0 += hv[j] * w.x; a1 += hv[j] * w.y; a2 += hv[j] * w.z; a3 += hv[j] * w.w;
    }
#pragma unroll
    for (int off = 32; off; off >>= 1) {
        a0 += __shfl_xor(a0, off);
        a1 += __shfl_xor(a1, off);
        a2 += __shfl_xor(a2, off);
        a3 += __shfl_xor(a3, off);
    }
    if (lane == 0) {
        float v[4] = {a0, a1, a2, a3};
        int e0 = 0; float b = v[0];
#pragma unroll
        for (int e = 1; e < 4; e++) if (v[e] > b) { b = v[e]; e0 = e; }
        int e1 = -1; float b2 = -1e30f;
#pragma unroll
        for (int e = 0; e < 4; e++) if (e != e0 && v[e] > b2) { b2 = v[e]; e1 = e; }
        float x = expf(b2 - b);
        float s = 1.f + x;
        sel[2 * n] = e0; sel[2 * n + 1] = e1;
        gv[2 * n] = 1.f / s; gv[2 * n + 1] = x / s;
    }
}

// ---------------- single-block scan (1024 thr): shfl scans + LDS-staged coalesced outputs ----------------
// ctl: [8..11]=expert base, [12]=total, [13]=n160 tiles (ffn2), [14]=n288 tiles (ffn1)
__global__ __launch_bounds__(1024) void k_scan(const int* __restrict__ sel,
                                               int* __restrict__ ctl, int* __restrict__ rtok,
                                               int* __restrict__ slotof,
                                               int* __restrict__ tiles, int* __restrict__ tiles2) {
    __shared__ int wtot[4][16];
    __shared__ int wbase[4][16];
    __shared__ int ebase[4];
    __shared__ int sL[16384];
    int t = threadIdx.x, w = t >> 6, lane = t & 63;
    int c[4] = {0, 0, 0, 0};
    int selloc[16];
    const int4* s4 = (const int4*)sel;
#pragma unroll
    for (int i = 0; i < 4; i++) {
        int4 v = s4[t * 4 + i];
        selloc[i * 4 + 0] = v.x; c[v.x]++;
        selloc[i * 4 + 1] = v.y; c[v.y]++;
        selloc[i * 4 + 2] = v.z; c[v.z]++;
        selloc[i * 4 + 3] = v.w; c[v.w]++;
    }
    int inc[4] = {c[0], c[1], c[2], c[3]};
#pragma unroll
    for (int off = 1; off < 64; off <<= 1) {
#pragma unroll
        for (int e = 0; e < 4; e++) {
            int v = __shfl_up(inc[e], off);
            if (lane >= off) inc[e] += v;
        }
    }
    if (lane == 63)
#pragma unroll
        for (int e = 0; e < 4; e++) wtot[e][w] = inc[e];
    __syncthreads();
    if (t == 0) {
        int o = 0, n160 = 0, n288 = 0;
#pragma unroll
        for (int e = 0; e < 4; e++) {
            int s = 0;
            for (int ww = 0; ww < 16; ww++) { wbase[e][ww] = s; s += wtot[e][ww]; }
            ebase[e] = o; ctl[8 + e] = o;
            for (int m0 = 0; m0 < s; m0 += 160) tiles[n160++] = (e << 16) | m0;
            for (int m0 = 0; m0 < s; m0 += 288) tiles2[n288++] = (e << 16) | m0;
            o += s;
        }
        ctl[12] = o; ctl[13] = n160; ctl[14] = n288;
    }
    __syncthreads();
    int pos[4];
#pragma unroll
    for (int e = 0; e < 4; e++) pos[e] = ebase[e] + wbase[e][w] + inc[e] - c[e];  // exclusive
    int slots[16];
#pragma unroll
    for (int i = 0; i < 16; i++) slots[i] = pos[selloc[i]]++;
#pragma unroll
    for (int i = 0; i < 4; i++) {
        int4 v; v.x = slots[4 * i]; v.y = slots[4 * i + 1]; v.z = slots[4 * i + 2]; v.w = slots[4 * i + 3];
        *(int4*)&slotof[t * 16 + i * 4] = v;
    }
#pragma unroll
    for (int i = 0; i < 16; i++) sL[slots[i]] = t * 16 + i;
    __syncthreads();
#pragma unroll
    for (int p = 0; p < 4; p++)
        *(int4*)&rtok[p * 4096 + t * 4] = *(const int4*)&sL[p * 4096 + t * 4];
}

// ---- grouped GEMM 1: 288x256, BK=64, 2-slot dbuf, 2-phase per-m-streamed A, chunk-counted vmcnt ----
// mid = relu(gather(h) @ w1[e] + b1[e]); 8 waves of 144x64 (2Mx4N).
// 9 chunks/K-tile/thread: A c0..c4 (c4 = 32 real rows + dup-pad) + B c0..c3. Byte-offset compressed addrs.
// Register-lean: bf[4][2] held (32 regs), af streamed per-m (8 regs) -> ~220 live vs R7's ~270 (spill fix).
// P0 (frags 0..4, rows wm..wm+80 use chunks A0..A3): wait vmcnt(1); issue next B0..3 mid-loop.
// P1 (frags 5..8, rows wm+80..wm+144 use A3,A4):      wait vmcnt(4); issue next A0..4 mid-loop.
__global__ __launch_bounds__(512, 2) void k_ffn1(
    const unsigned short* __restrict__ hb, const unsigned short* __restrict__ w1t,
    const float* __restrict__ b1, const int* __restrict__ ctl, const int* __restrict__ tiles2,
    const int* __restrict__ rtok, unsigned short* __restrict__ mid) {
    int flat = blockIdx.x;
    int c8 = flat & 7, q = flat >> 3;
    int nt = q & 7, mt = (q >> 3) * 8 + c8;
    if (mt >= ctl[14]) return;
    int tv = tiles2[mt];
    int e = tv >> 16, m0 = tv & 0xFFFF;
    int base = ctl[8 + e];
    int cnt = ctl[9 + e] - base;
    int n0 = nt * 256;

    __shared__ unsigned short sm[2 * SLOT1];   // 139 KB dbuf; epilogue half-repack (144 x RP1) aliases
    __shared__ int toks[288];

    int t = threadIdx.x;
    if (t < 288) {
        int r = m0 + t; if (r >= cnt) r = cnt - 1;
        toks[t] = rtok[base + r] >> 1;
    }
    __syncthreads();

    const char* hbB = (const char*)hb;                          // uniform bases (SGPR)
    const char* wBB = (const char*)(w1t + (size_t)e * HH * DD);
    // A: 288 rows x 8 granules of 16B = 2304 lane-slots; chunk 4 = rows 256..288 (t<256) + dup of
    // chunk-0 rows 32..64 (t>=256; identical src+dst -> benign, keeps per-thread counts uniform)
    int idxA[5];
#pragma unroll
    for (int r = 0; r < 4; r++) idxA[r] = r * 512 + t;
    idxA[4] = (t < 256) ? (2048 + t) : t;
    int offA[5], lofA[5];                                       // 32-bit byte offsets
#pragma unroll
    for (int r = 0; r < 5; r++) {
        int row = idxA[r] >> 3, sch = idxA[r] & 7;
        int cg = (sch - row) & 7;
        offA[r] = (toks[row] * DD + cg * 8) * 2;
        lofA[r] = idxA[r] * 8;
    }
    int offB[4], lofB[4];
#pragma unroll
    for (int r = 0; r < 4; r++) {
        int idx = r * 512 + t;
        int row = idx >> 3, sch = idx & 7;
        int cg = (sch - row) & 7;
        offB[r] = ((n0 + row) * DD + cg * 8) * 2;
        lofB[r] = ASZ1 + idx * 8;
    }

    int w = t >> 6, lane = t & 63;
    int wm = (w >> 2) * 144, wn = (w & 3) * 64;   // wave tile 144x64
    int lrow = lane & 15, quad = lane >> 4;

    floatx4 acc[9][4];
#pragma unroll
    for (int i = 0; i < 9; i++)
#pragma unroll
        for (int j = 0; j < 4; j++) acc[i][j] = (floatx4)0.f;

    // prologue: stage K-tile 0 (B0..3 then A0..4 — FIFO order matches the steady-state count math)
#pragma unroll
    for (int r = 0; r < 4; r++) gld_lds16((const unsigned short*)(wBB + offB[r]), sm + lofB[r]);
#pragma unroll
    for (int r = 0; r < 5; r++) gld_lds16((const unsigned short*)(hbB + offA[r]), sm + lofA[r]);

    const int NK = DD / 64;   // 8
    for (int tt = 0; tt < NK; tt++) {
        const unsigned short* SA = sm + (tt & 1) * SLOT1;
        const unsigned short* SB = SA + ASZ1;
        unsigned short* sb = sm + ((tt + 1) & 1) * SLOT1;
        int kb = (tt + 1) * 128;                   // K byte offset of next tile
        bool more = (tt + 1 < NK);

        // ---------- P0: A frags 0..4 x all B cols ----------
        asm volatile("s_waitcnt vmcnt(1)" ::: "memory");   // tile tt's B0-3,A0-3 landed (A4 may pend)
        __builtin_amdgcn_s_barrier();
        asm volatile("" ::: "memory");
        short8 bf[4][2];
#pragma unroll
        for (int j = 0; j < 4; j++)
#pragma unroll
            for (int ks = 0; ks < 2; ks++) {
                int row = wn + 16 * j + lrow;
                bf[j][ks] = *(const short8*)&SB[row * 64 + (((ks << 2) + quad + row) & 7) * 8];
            }
#pragma unroll
        for (int m = 0; m < 5; m++) {
            int row = wm + 16 * m + lrow;
            short8 a0 = *(const short8*)&SA[row * 64 + ((quad + row) & 7) * 8];
            short8 a1 = *(const short8*)&SA[row * 64 + ((4 + quad + row) & 7) * 8];
            if (more) {
                if (m == 1) { gld_lds16((const unsigned short*)(wBB + offB[0] + kb), sb + lofB[0]);
                              gld_lds16((const unsigned short*)(wBB + offB[1] + kb), sb + lofB[1]); }
                if (m == 3) { gld_lds16((const unsigned short*)(wBB + offB[2] + kb), sb + lofB[2]);
                              gld_lds16((const unsigned short*)(wBB + offB[3] + kb), sb + lofB[3]); }
            }
            __builtin_amdgcn_s_setprio(1);
#pragma unroll
            for (int j = 0; j < 4; j++) {
                acc[m][j] = __builtin_amdgcn_mfma_f32_16x16x32_bf16(a0, bf[j][0], acc[m][j], 0, 0, 0);
                acc[m][j] = __builtin_amdgcn_mfma_f32_16x16x32_bf16(a1, bf[j][1], acc[m][j], 0, 0, 0);
            }
            __builtin_amdgcn_s_setprio(0);
        }
        asm volatile("" ::: "memory");

        // ---------- P1: A frags 5..8 x all B cols ----------
        if (more) asm volatile("s_waitcnt vmcnt(4)" ::: "memory");   // cur A4 landed; next B0-3 in flight
        else      asm volatile("s_waitcnt vmcnt(0)" ::: "memory");
        __builtin_amdgcn_s_barrier();
        asm volatile("" ::: "memory");
#pragma unroll
        for (int m = 0; m < 4; m++) {
            int row = wm + 80 + 16 * m + lrow;
            short8 a0 = *(const short8*)&SA[row * 64 + ((quad + row) & 7) * 8];
            short8 a1 = *(const short8*)&SA[row * 64 + ((4 + quad + row) & 7) * 8];
            if (more) {
                if (m == 0) { gld_lds16((const unsigned short*)(hbB + offA[0] + kb), sb + lofA[0]);
                              gld_lds16((const unsigned short*)(hbB + offA[1] + kb), sb + lofA[1]); }
                if (m == 1) { gld_lds16((const unsigned short*)(hbB + offA[2] + kb), sb + lofA[2]);
                              gld_lds16((const unsigned short*)(hbB + offA[3] + kb), sb + lofA[3]); }
                if (m == 2) { gld_lds16((const unsigned short*)(hbB + offA[4] + kb), sb + lofA[4]); }
            }
            __builtin_amdgcn_s_setprio(1);
#pragma unroll
            for (int j = 0; j < 4; j++) {
                acc[5 + m][j] = __builtin_amdgcn_mfma_f32_16x16x32_bf16(a0, bf[j][0], acc[5 + m][j], 0, 0, 0);
                acc[5 + m][j] = __builtin_amdgcn_mfma_f32_16x16x32_bf16(a1, bf[j][1], acc[5 + m][j], 0, 0, 0);
            }
            __builtin_amdgcn_s_setprio(0);
        }
        asm volatile("" ::: "memory");
    }
    __syncthreads();   // full drain before repack aliases the slots

    // epilogue: bias + relu -> repack in two 144-row half-passes (76 KB alias) -> coalesced 128B stores
    float bias[4];
#pragma unroll
    for (int j = 0; j < 4; j++) bias[j] = b1[e * HH + n0 + wn + 16 * j + lrow];
#pragma unroll
    for (int half = 0; half < 2; half++) {
        if ((w >> 2) == half) {
#pragma unroll
            for (int j = 0; j < 4; j++) {
                int col = wn + 16 * j + lrow;
#pragma unroll
                for (int i = 0; i < 9; i++) {
#pragma unroll
                    for (int r = 0; r < 4; r++) {
                        int lr = ((i < 5) ? 16 * i : 80 + 16 * (i - 5)) + quad * 4 + r;
                        float v = acc[i][j][r] + bias[j];
                        v = v > 0.f ? v : 0.f;
                        sm[lr * RP1 + col] = f2bf(v);
                    }
                }
            }
        }
        __syncthreads();
        // 144 rows x 4 segs of 128B = 576 row-segs; 512 threads -> 2 iterations (2nd partial)
#pragma unroll
        for (int it = 0; it < 2; it++) {
            int idx = it * 512 + t;
            if (idx < 576) {
                int row = idx >> 2, seg = idx & 3;
                int grow = half * 144 + row;
                if (m0 + grow < cnt) {
                    unsigned short* dst = mid + (size_t)(base + m0 + grow) * HH + n0 + seg * 64;
                    const unsigned short* src = sm + row * RP1 + seg * 64;
#pragma unroll
                    for (int k = 0; k < 8; k++)
                        *(uint4*)(dst + k * 8) = *(const uint4*)(src + k * 8);
                }
            }
        }
        __syncthreads();
    }
}

// ---- grouped GEMM 2: 160x128, BK=64, 2-slot dbuf (72 KB -> 2 blk/CU, ~416 blocks ALL resident) ----
// ybuf[slot] = gate * (mid @ w2[e] + b2[e]); 8 waves of 80x32; 5 chunks/thread (3 A dup-pad + 2 B)
__global__ __launch_bounds__(512, 4) void k_ffn2(
    const unsigned short* __restrict__ mid, const unsigned short* __restrict__ w2t,
    const float* __restrict__ b2, const int* __restrict__ ctl, const int* __restrict__ tiles,
    const float* __restrict__ gv, const int* __restrict__ rtok, unsigned short* __restrict__ ybuf) {
    int flat = blockIdx.x;
    int c8 = flat & 7, q = flat >> 3;
    int nt = q & 3, mt = (q >> 2) * 8 + c8;
    if (mt >= ctl[13]) return;
    int tv = tiles[mt];
    int e = tv >> 16, m0 = tv & 0xFFFF;
    int base = ctl[8 + e];
    int cnt = ctl[9 + e] - base;
    int n0 = nt * 128;

    __shared__ unsigned short sm[2 * SLOT2];   // 72 KB dbuf; epilogue repack (160 x RP2) aliases
    __shared__ float gts[160];

    int t = threadIdx.x;
    if (t < 160) {
        int r = m0 + t; if (r >= cnt) r = cnt - 1;
        gts[t] = gv[rtok[base + r]];
    }
    __syncthreads();

    const unsigned short* wB = w2t + (size_t)e * DD * HH;
    int idxA[3]; idxA[0] = t; idxA[1] = 512 + t; idxA[2] = (t < 256) ? (1024 + t) : (512 + t);
    const unsigned short* gA[3]; int lofA[3];
#pragma unroll
    for (int r = 0; r < 3; r++) {
        int row = idxA[r] >> 3, sch = idxA[r] & 7;
        int cg = (sch - row) & 7;
        int ra = m0 + row; if (ra >= cnt) ra = cnt - 1;
        gA[r] = mid + (size_t)(base + ra) * HH + cg * 8;
        lofA[r] = idxA[r] * 8;
    }
    const unsigned short* gB[2]; int lofB[2];
#pragma unroll
    for (int r = 0; r < 2; r++) {
        int idx = r * 512 + t;
        int row = idx >> 3, sch = idx & 7;
        int cg = (sch - row) & 7;
        gB[r] = wB + (size_t)(n0 + row) * HH + cg * 8;
        lofB[r] = ASZ2 + idx * 8;
    }

    int w = t >> 6, lane = t & 63;
    int wm = (w >> 2) * 80, wn = (w & 3) * 32;   // wave tile 80x32
    int lrow = lane & 15, quad = lane >> 4;

    floatx4 acc[5][2];
#pragma unroll
    for (int i = 0; i < 5; i++)
#pragma unroll
        for (int j = 0; j < 2; j++) acc[i][j] = (floatx4)0.f;

    // prologue: stage K-tile 0 (A then B)
#pragma unroll
    for (int r = 0; r < 3; r++) gld_lds16(gA[r], sm + lofA[r]);
#pragma unroll
    for (int r = 0; r < 2; r++) gld_lds16(gB[r], sm + lofB[r]);

    const int NK = HH / 64;   // 32
    for (int tt = 0; tt < NK; tt++) {
        const unsigned short* SA = sm + (tt & 1) * SLOT2;
        const unsigned short* SB = SA + ASZ2;
        unsigned short* sb = sm + ((tt + 1) & 1) * SLOT2;
        int k1 = (tt + 1) * 64;
        bool more = (tt + 1 < NK);

        if (more) {
#pragma unroll
            for (int r = 0; r < 3; r++) gld_lds16(gA[r] + k1, sb + lofA[r]);
            asm volatile("s_waitcnt vmcnt(3)" ::: "memory");   // tile tt's 5 chunks landed
        } else {
            asm volatile("s_waitcnt vmcnt(0)" ::: "memory");
        }
        __builtin_amdgcn_s_barrier();
        asm volatile("" ::: "memory");

        short8 af[5][2], bf[2][2];
#pragma unroll
        for (int i = 0; i < 5; i++)
#pragma unroll
            for (int ks = 0; ks < 2; ks++) {
                int row = wm + 16 * i + lrow;
                af[i][ks] = *(const short8*)&SA[row * 64 + (((ks << 2) + quad + row) & 7) * 8];
            }
#pragma unroll
        for (int j = 0; j < 2; j++)
#pragma unroll
            for (int ks = 0; ks < 2; ks++) {
                int row = wn + 16 * j + lrow;
                bf[j][ks] = *(const short8*)&SB[row * 64 + (((ks << 2) + quad + row) & 7) * 8];
            }
        if (more) { gld_lds16(gB[0] + k1, sb + lofB[0]); gld_lds16(gB[1] + k1, sb + lofB[1]); }
        __builtin_amdgcn_s_setprio(1);
#pragma unroll
        for (int i = 0; i < 5; i++)
#pragma unroll
            for (int j = 0; j < 2; j++)
#pragma unroll
                for (int ks = 0; ks < 2; ks++)
                    acc[i][j] = __builtin_amdgcn_mfma_f32_16x16x32_bf16(af[i][ks], bf[j][ks], acc[i][j], 0, 0, 0);
        __builtin_amdgcn_s_setprio(0);
        asm volatile("" ::: "memory");
        __builtin_amdgcn_s_barrier();
        asm volatile("" ::: "memory");
    }
    __syncthreads();

    // epilogue: bias + gate-scale -> repack (160 x RP2) -> coalesced stores
    float b2v[2];
#pragma unroll
    for (int j = 0; j < 2; j++) b2v[j] = b2[e * DD + n0 + wn + 16 * j + lrow];
#pragma unroll
    for (int j = 0; j < 2; j++) {
        int col = wn + 16 * j + lrow;
#pragma unroll
        for (int i = 0; i < 5; i++) {
#pragma unroll
            for (int r = 0; r < 4; r++) {
                int m = wm + 16 * i + quad * 4 + r;
                float v = (acc[i][j][r] + b2v[j]) * gts[m];
                sm[m * RP2 + col] = f2bf(v);
            }
        }
    }
    __syncthreads();
    {
        int row = t >> 1, half = t & 1;   // rows 0..159 x 2 segs of 128B (t < 320 active)
        if (row < 160 && m0 + row < cnt) {
            unsigned short* dst = ybuf + (size_t)(base + m0 + row) * DD + n0 + half * 64;
            const unsigned short* src = sm + row * RP2 + half * 64;
#pragma unroll
            for (int k = 0; k < 8; k++)
                *(uint4*)(dst + k * 8) = *(const uint4*)(src + k * 8);
        }
    }
}

// ---------------- combine (512 thr, 4 tokens/block): out[n] = ybuf[slot(n,0)] + ybuf[slot(n,1)] ----------------
__global__ __launch_bounds__(512) void k_combine(const unsigned short* __restrict__ ybuf,
                                                 const int* __restrict__ slotof,
                                                 float* __restrict__ out) {
    int n = blockIdx.x * 4 + (threadIdx.x >> 7);
    int c = (threadIdx.x & 127) * 4;
    int sA = slotof[2 * n], sB = slotof[2 * n + 1];
    ushort4 a = *(const ushort4*)(ybuf + (size_t)sA * DD + c);
    ushort4 b = *(const ushort4*)(ybuf + (size_t)sB * DD + c);
    float4 o;
    o.x = bf2f(a.x) + bf2f(b.x);
    o.y = bf2f(a.y) + bf2f(b.y);
    o.z = bf2f(a.z) + bf2f(b.z);
    o.w = bf2f(a.w) + bf2f(b.w);
    *(float4*)(out + (size_t)n * DD + c) = o;
}

extern "C" void kernel_launch(void* const* d_in, const int* in_sizes, int n_in,
                              void* d_out, int out_size, void* d_ws, size_t ws_size,
                              hipStream_t stream) {
    const float* h  = (const float*)d_in[0];
    const float* wg = (const float*)d_in[1];
    const float* w1 = (const float*)d_in[2];
    const float* b1 = (const float*)d_in[3];
    const float* w2 = (const float*)d_in[4];
    const float* b2 = (const float*)d_in[5];
    float* out = (float*)d_out;

    char* ws = (char*)d_ws;
    size_t off = 0;
    auto alloc = [&](size_t bytes) -> void* {
        void* p = ws + off;
        off += (bytes + 255) & ~(size_t)255;
        return p;
    };
    unsigned short* hb  = (unsigned short*)alloc((size_t)NT * DD * 2);        // dead after ffn1
    unsigned short* w1t = (unsigned short*)alloc((size_t)NE * HH * DD * 2);   // dead after ffn1
    unsigned short* w2t = (unsigned short*)alloc((size_t)NE * DD * HH * 2);
    int*   sel    = (int*)alloc((size_t)NT * 2 * 4);
    float* gv     = (float*)alloc((size_t)NT * 2 * 4);
    int*   ctl    = (int*)alloc(256);
    int*   tiles  = (int*)alloc(1024);
    int*   tiles2 = (int*)alloc(1024);
    int*   rtok   = (int*)alloc((size_t)NT * 2 * 4);
    int*   slotof = (int*)alloc((size_t)NT * 2 * 4);
    unsigned short* mid = (unsigned short*)alloc((size_t)NT * 2 * HH * 2);
    // ybuf [NT*2][DD] bf16 (16.7 MB) aliases hb+w1t (16.7 MB), both dead before ffn2 runs
    unsigned short* ybuf = (unsigned short*)ws;

    k_prep<<<dim3(2048 + NT / 8), 512, 0, stream>>>(w1, w1t, w2, w2t, h, wg, sel, gv, hb);
    k_scan<<<1, 1024, 0, stream>>>(sel, ctl, rtok, slotof, tiles, tiles2);
    k_ffn1<<<dim3(FFN1_GRID), 512, 0, stream>>>(hb, w1t, b1, ctl, tiles2, rtok, mid);
    k_ffn2<<<dim3(FFN2_GRID), 512, 0, stream>>>(mid, w2t, b2, ctl, tiles, gv, rtok, ybuf);
    k_combine<<<dim3(NT / 4), 512, 0, stream>>>(ybuf, slotof, out);
}

// Round 9
// 217.765 us; speedup vs baseline: 1.0670x; 1.0670x over previous
//
#include <hip/hip_runtime.h>
#include <hip/hip_bf16.h>
#include <cstdint>
#include <cstddef>

// Problem constants
#define NT 8192
#define DD 512
#define HH 2048
#define NE 4
// ffn1: BM=288,BN=256,BK=64, 2-slot dbuf (139 KB, 1 blk/CU), 4-phase, chunk-counted vmcnt (R7 proven, 66.7us)
#define ASZ1  18432    // A slot shorts: 288x64
#define SLOT1 34816    // + B 256x64 (16384)
// ffn2: BM=160,BN=128,BK=64, 2-slot dbuf (72 KB, 2 blk/CU), ~416 blocks ALL co-resident
#define SLOT2 18432    // shorts: A 160x64 (10240) + B 128x64 (8192)
#define ASZ2  10240
#define RP1 264        // ffn1 repack row stride (shorts)
#define RP2 136        // ffn2 repack row stride (shorts)
#define FFN1_GRID 512  // 8 mt-groups x 8 xcd x 8 n-tiles (capacity 64 m-tiles of 288; worst case 60)
#define FFN2_GRID 448  // 14 mt-groups x 8 xcd x 4 n-tiles

typedef short short8 __attribute__((ext_vector_type(8)));
typedef float floatx4 __attribute__((ext_vector_type(4)));

static __device__ __forceinline__ unsigned short f2bf(float f) {
    union { float f; uint32_t u; } v; v.f = f;
    uint32_t u = v.u;
    u += 0x7FFFu + ((u >> 16) & 1u);   // round-to-nearest-even
    return (unsigned short)(u >> 16);
}
static __device__ __forceinline__ float bf2f(unsigned short u) {
    union { uint32_t u; float f; } v; v.u = ((uint32_t)u) << 16; return v.f;
}

// async global->LDS, 16B per lane. LDS dest = wave-uniform base + lane*16 (addresses below are lane-linear).
static __device__ __forceinline__ void gld_lds16(const unsigned short* g, unsigned short* l) {
    __builtin_amdgcn_global_load_lds(
        (const __attribute__((address_space(1))) void*)g,
        (__attribute__((address_space(3))) void*)l, 16, 0, 0);
}

// ------------- gate (512 thr, 8 tokens/block): fp32 logits, exact top-2, fused h->bf16 cast -------------
__global__ __launch_bounds__(512) void k_gate(
    const float* __restrict__ h, const float* __restrict__ wg,
    int* __restrict__ sel, float* __restrict__ gv, unsigned short* __restrict__ hb) {
    int t = threadIdx.x;
    int wid = t >> 6, lane = t & 63;
    int n = blockIdx.x * 8 + wid;
    const float* hr = h + (size_t)n * DD;
    int d0 = lane * 8;
    float hv[8];
    *(float4*)(hv)     = *(const float4*)(hr + d0);
    *(float4*)(hv + 4) = *(const float4*)(hr + d0 + 4);
    unsigned short tmp[8];
#pragma unroll
    for (int j = 0; j < 8; j++) tmp[j] = f2bf(hv[j]);
    *(uint4*)(hb + (size_t)n * DD + d0) = *(const uint4*)tmp;

    float a0 = 0.f, a1 = 0.f, a2 = 0.f, a3 = 0.f;
#pragma unroll
    for (int j = 0; j < 8; j++) {
        float4 w = *(const float4*)(wg + (size_t)(d0 + j) * 4);
        a0 += hv[j] * w.x; a1 += hv[j] * w.y; a2 += hv[j] * w.z; a3 += hv[j] * w.w;
    }
#pragma unroll
    for (int off = 32; off; off >>= 1) {
        a0 += __shfl_xor(a0, off);
        a1 += __shfl_xor(a1, off);
        a2 += __shfl_xor(a2, off);
        a3 += __shfl_xor(a3, off);
    }
    if (lane == 0) {
        float v[4] = {a0, a1, a2, a3};
        int e0 = 0; float b = v[0];
#pragma unroll
        for (int e = 1; e < 4; e++) if (v[e] > b) { b = v[e]; e0 = e; }
        int e1 = -1; float b2 = -1e30f;
#pragma unroll
        for (int e = 0; e < 4; e++) if (e != e0 && v[e] > b2) { b2 = v[e]; e1 = e; }
        float x = expf(b2 - b);
        float s = 1.f + x;
        sel[2 * n] = e0; sel[2 * n + 1] = e1;
        gv[2 * n] = 1.f / s; gv[2 * n + 1] = x / s;
    }
}

// ------- scan + weight-transpose fused (1024 thr): block 0 = scan (1 CU); blocks 1..1024 = 2 tiles each -------
// The single-block scan's serial time hides under the transpose work instead of serializing the device.
// ctl: [8..11]=expert base, [12]=total, [13]=n160 tiles (ffn2), [14]=n288 tiles (ffn1)
__global__ __launch_bounds__(1024) void k_scanT(
    const int* __restrict__ sel, int* __restrict__ ctl, int* __restrict__ rtok,
    int* __restrict__ slotof, int* __restrict__ tiles, int* __restrict__ tiles2,
    const float* __restrict__ w1, unsigned short* __restrict__ w1t,
    const float* __restrict__ w2, unsigned short* __restrict__ w2t) {
    __shared__ int wtot[4][16];
    __shared__ int wbase[4][16];
    __shared__ int ebase[4];
    __shared__ __align__(16) char big[65536];   // scan: sL[16384] ints | transpose: 2x 64x65 floats
    int t = threadIdx.x;

    if (blockIdx.x != 0) {
        // ---- two 64x64 transpose tiles (col-major LDS, S=65, conflict-free; 16B global access) ----
        int half = t >> 9, t5 = t & 511;
        int tt = (blockIdx.x - 1) * 2 + half;     // 0..2047
        int z = tt >> 8, rem = tt & 255;          // 256 tiles per expert-matrix
        const float* in; unsigned short* out; int R, C, by, bx;
        if (z < 4) {
            in = w1 + (size_t)z * DD * HH; out = w1t + (size_t)z * DD * HH;
            R = DD; C = HH; by = rem >> 5; bx = rem & 31;      // 8 x 32 tiles
        } else {
            in = w2 + (size_t)(z - 4) * HH * DD; out = w2t + (size_t)(z - 4) * HH * DD;
            R = HH; C = DD; by = rem >> 3; bx = rem & 7;       // 32 x 8 tiles
        }
        int r0 = by * 64, c0 = bx * 64;
        float* tl = (float*)big + half * 4160;    // 64*65
        int rr = t5 >> 4, c4 = (t5 & 15) * 4;
#pragma unroll
        for (int p = 0; p < 2; p++) {
            int r = rr + p * 32;
            float4 v = *(const float4*)(in + (size_t)(r0 + r) * C + c0 + c4);
            tl[(c4 + 0) * 65 + r] = v.x;
            tl[(c4 + 1) * 65 + r] = v.y;
            tl[(c4 + 2) * 65 + r] = v.z;
            tl[(c4 + 3) * 65 + r] = v.w;
        }
        __syncthreads();
        int c = t5 >> 3, seg = t5 & 7;
        unsigned short tmp[8];
#pragma unroll
        for (int k = 0; k < 8; k++) tmp[k] = f2bf(tl[c * 65 + seg * 8 + k]);
        *(uint4*)(out + (size_t)(c0 + c) * R + r0 + seg * 8) = *(const uint4*)tmp;
        return;
    }

    // ---- block 0: scan (shfl scans + LDS-staged coalesced outputs) ----
    int* sL = (int*)big;
    int w = t >> 6, lane = t & 63;
    int c[4] = {0, 0, 0, 0};
    int selloc[16];
    const int4* s4 = (const int4*)sel;
#pragma unroll
    for (int i = 0; i < 4; i++) {
        int4 v = s4[t * 4 + i];
        selloc[i * 4 + 0] = v.x; c[v.x]++;
        selloc[i * 4 + 1] = v.y; c[v.y]++;
        selloc[i * 4 + 2] = v.z; c[v.z]++;
        selloc[i * 4 + 3] = v.w; c[v.w]++;
    }
    int inc[4] = {c[0], c[1], c[2], c[3]};
#pragma unroll
    for (int off = 1; off < 64; off <<= 1) {
#pragma unroll
        for (int e = 0; e < 4; e++) {
            int v = __shfl_up(inc[e], off);
            if (lane >= off) inc[e] += v;
        }
    }
    if (lane == 63)
#pragma unroll
        for (int e = 0; e < 4; e++) wtot[e][w] = inc[e];
    __syncthreads();
    if (t == 0) {
        int o = 0, n160 = 0, n288 = 0;
#pragma unroll
        for (int e = 0; e < 4; e++) {
            int s = 0;
            for (int ww = 0; ww < 16; ww++) { wbase[e][ww] = s; s += wtot[e][ww]; }
            ebase[e] = o; ctl[8 + e] = o;
            for (int m0 = 0; m0 < s; m0 += 160) tiles[n160++] = (e << 16) | m0;
            for (int m0 = 0; m0 < s; m0 += 288) tiles2[n288++] = (e << 16) | m0;
            o += s;
        }
        ctl[12] = o; ctl[13] = n160; ctl[14] = n288;
    }
    __syncthreads();
    int pos[4];
#pragma unroll
    for (int e = 0; e < 4; e++) pos[e] = ebase[e] + wbase[e][w] + inc[e] - c[e];  // exclusive
    int slots[16];
#pragma unroll
    for (int i = 0; i < 16; i++) slots[i] = pos[selloc[i]]++;
#pragma unroll
    for (int i = 0; i < 4; i++) {
        int4 v; v.x = slots[4 * i]; v.y = slots[4 * i + 1]; v.z = slots[4 * i + 2]; v.w = slots[4 * i + 3];
        *(int4*)&slotof[t * 16 + i * 4] = v;
    }
#pragma unroll
    for (int i = 0; i < 16; i++) sL[slots[i]] = t * 16 + i;
    __syncthreads();
#pragma unroll
    for (int p = 0; p < 4; p++)
        *(int4*)&rtok[p * 4096 + t * 4] = *(const int4*)&sL[p * 4096 + t * 4];
}

// ---- grouped GEMM 1 (R7 proven, 66.7us): 288x256, BK=64, 2-slot dbuf, 4-phase, chunk-counted vmcnt ----
// mid = relu(gather(h) @ w1[e] + b1[e]); 8 waves of 144x64 (2Mx4N).
// 9 chunks/K-tile/thread: A c0..c4 (c4 = 32 real rows + dup-pad) + B c0..c3.
// Issue: tile t+1's B01 in P0, B23 in P1, A0..A4 in P2. Waits: P0 vmcnt(1); P2 vmcnt(4).
__global__ __launch_bounds__(512, 2) void k_ffn1(
    const unsigned short* __restrict__ hb, const unsigned short* __restrict__ w1t,
    const float* __restrict__ b1, const int* __restrict__ ctl, const int* __restrict__ tiles2,
    const int* __restrict__ rtok, unsigned short* __restrict__ mid) {
    int flat = blockIdx.x;
    int c8 = flat & 7, q = flat >> 3;
    int nt = q & 7, mt = (q >> 3) * 8 + c8;
    if (mt >= ctl[14]) return;
    int tv = tiles2[mt];
    int e = tv >> 16, m0 = tv & 0xFFFF;
    int base = ctl[8 + e];
    int cnt = ctl[9 + e] - base;
    int n0 = nt * 256;

    __shared__ unsigned short sm[2 * SLOT1];   // 139 KB dbuf; epilogue half-repack (144 x RP1) aliases
    __shared__ int toks[288];

    int t = threadIdx.x;
    if (t < 288) {
        int r = m0 + t; if (r >= cnt) r = cnt - 1;
        toks[t] = rtok[base + r] >> 1;
    }
    __syncthreads();

    const unsigned short* wB = w1t + (size_t)e * HH * DD;
    int idxA[5];
#pragma unroll
    for (int r = 0; r < 4; r++) idxA[r] = r * 512 + t;
    idxA[4] = (t < 256) ? (2048 + t) : t;
    const unsigned short* gA[5]; int lofA[5];
#pragma unroll
    for (int r = 0; r < 5; r++) {
        int row = idxA[r] >> 3, sch = idxA[r] & 7;
        int cg = (sch - row) & 7;
        gA[r] = hb + (size_t)toks[row] * DD + cg * 8;
        lofA[r] = idxA[r] * 8;
    }
    const unsigned short* gB[4]; int lofB[4];
#pragma unroll
    for (int r = 0; r < 4; r++) {
        int idx = r * 512 + t;
        int row = idx >> 3, sch = idx & 7;
        int cg = (sch - row) & 7;
        gB[r] = wB + (size_t)(n0 + row) * DD + cg * 8;
        lofB[r] = ASZ1 + idx * 8;
    }

    int w = t >> 6, lane = t & 63;
    int wm = (w >> 2) * 144, wn = (w & 3) * 64;   // wave tile 144x64
    int lrow = lane & 15, quad = lane >> 4;

    floatx4 acc[9][4];
#pragma unroll
    for (int i = 0; i < 9; i++)
#pragma unroll
        for (int j = 0; j < 4; j++) acc[i][j] = (floatx4)0.f;

    // prologue: stage K-tile 0 (B0..3 then A0..4 — FIFO order matches the steady-state count math)
#pragma unroll
    for (int r = 0; r < 4; r++) gld_lds16(gB[r], sm + lofB[r]);
#pragma unroll
    for (int r = 0; r < 5; r++) gld_lds16(gA[r], sm + lofA[r]);

    const int NK = DD / 64;   // 8
    for (int tt = 0; tt < NK; tt++) {
        const unsigned short* SA = sm + (tt & 1) * SLOT1;
        const unsigned short* SB = SA + ASZ1;
        unsigned short* sb = sm + ((tt + 1) & 1) * SLOT1;
        int k1 = (tt + 1) * 64;
        bool more = (tt + 1 < NK);
        short8 af[5][2], bf[4][2];

        // ---------- P0: A frags 0..4 (rows wm..wm+80) x B cols wn..wn+32 ----------
        asm volatile("s_waitcnt vmcnt(1)" ::: "memory");   // tile tt's B0-3,A0-3 landed (A4 may pend)
        __builtin_amdgcn_s_barrier();
        asm volatile("" ::: "memory");
#pragma unroll
        for (int i = 0; i < 5; i++)
#pragma unroll
            for (int ks = 0; ks < 2; ks++) {
                int row = wm + 16 * i + lrow;
                af[i][ks] = *(const short8*)&SA[row * 64 + (((ks << 2) + quad + row) & 7) * 8];
            }
#pragma unroll
        for (int j = 0; j < 2; j++)
#pragma unroll
            for (int ks = 0; ks < 2; ks++) {
                int row = wn + 16 * j + lrow;
                bf[j][ks] = *(const short8*)&SB[row * 64 + (((ks << 2) + quad + row) & 7) * 8];
            }
        if (more) { gld_lds16(gB[0] + k1, sb + lofB[0]); gld_lds16(gB[1] + k1, sb + lofB[1]); }
        __builtin_amdgcn_s_setprio(1);
#pragma unroll
        for (int i = 0; i < 5; i++)
#pragma unroll
            for (int j = 0; j < 2; j++)
#pragma unroll
                for (int ks = 0; ks < 2; ks++)
                    acc[i][j] = __builtin_amdgcn_mfma_f32_16x16x32_bf16(af[i][ks], bf[j][ks], acc[i][j], 0, 0, 0);
        __builtin_amdgcn_s_setprio(0);
        asm volatile("" ::: "memory");

        // ---------- P1: A frags 0..4 x B cols wn+32..wn+64 ----------
        __builtin_amdgcn_s_barrier();
        asm volatile("" ::: "memory");
#pragma unroll
        for (int j = 2; j < 4; j++)
#pragma unroll
            for (int ks = 0; ks < 2; ks++) {
                int row = wn + 16 * j + lrow;
                bf[j][ks] = *(const short8*)&SB[row * 64 + (((ks << 2) + quad + row) & 7) * 8];
            }
        if (more) { gld_lds16(gB[2] + k1, sb + lofB[2]); gld_lds16(gB[3] + k1, sb + lofB[3]); }
        __builtin_amdgcn_s_setprio(1);
#pragma unroll
        for (int i = 0; i < 5; i++)
#pragma unroll
            for (int j = 2; j < 4; j++)
#pragma unroll
                for (int ks = 0; ks < 2; ks++)
                    acc[i][j] = __builtin_amdgcn_mfma_f32_16x16x32_bf16(af[i][ks], bf[j][ks], acc[i][j], 0, 0, 0);
        __builtin_amdgcn_s_setprio(0);
        asm volatile("" ::: "memory");

        // ---------- P2: A frags 5..8 (rows wm+80..wm+144) x B cols wn..wn+32 ----------
        if (more) asm volatile("s_waitcnt vmcnt(4)" ::: "memory");   // cur A4 landed; next B0-3 in flight
        else      asm volatile("s_waitcnt vmcnt(0)" ::: "memory");
        __builtin_amdgcn_s_barrier();
        asm volatile("" ::: "memory");
#pragma unroll
        for (int i = 0; i < 4; i++)
#pragma unroll
            for (int ks = 0; ks < 2; ks++) {
                int row = wm + 80 + 16 * i + lrow;
                af[i][ks] = *(const short8*)&SA[row * 64 + (((ks << 2) + quad + row) & 7) * 8];
            }
        if (more) {
#pragma unroll
            for (int r = 0; r < 5; r++) gld_lds16(gA[r] + k1, sb + lofA[r]);
        }
        __builtin_amdgcn_s_setprio(1);
#pragma unroll
        for (int i = 0; i < 4; i++)
#pragma unroll
            for (int j = 0; j < 2; j++)
#pragma unroll
                for (int ks = 0; ks < 2; ks++)
                    acc[5 + i][j] = __builtin_amdgcn_mfma_f32_16x16x32_bf16(af[i][ks], bf[j][ks], acc[5 + i][j], 0, 0, 0);
        __builtin_amdgcn_s_setprio(0);
        asm volatile("" ::: "memory");

        // ---------- P3: A frags 5..8 x B cols wn+32..wn+64 ----------
        __builtin_amdgcn_s_barrier();
        asm volatile("" ::: "memory");
        __builtin_amdgcn_s_setprio(1);
#pragma unroll
        for (int i = 0; i < 4; i++)
#pragma unroll
            for (int j = 2; j < 4; j++)
#pragma unroll
                for (int ks = 0; ks < 2; ks++)
                    acc[5 + i][j] = __builtin_amdgcn_mfma_f32_16x16x32_bf16(af[i][ks], bf[j][ks], acc[5 + i][j], 0, 0, 0);
        __builtin_amdgcn_s_setprio(0);
        asm volatile("" ::: "memory");
    }
    __syncthreads();   // full drain before repack aliases the slots

    // epilogue: bias + relu -> repack in two 144-row half-passes (76 KB alias) -> coalesced 128B stores
    float bias[4];
#pragma unroll
    for (int j = 0; j < 4; j++) bias[j] = b1[e * HH + n0 + wn + 16 * j + lrow];
#pragma unroll
    for (int half = 0; half < 2; half++) {
        if ((w >> 2) == half) {
#pragma unroll
            for (int j = 0; j < 4; j++) {
                int col = wn + 16 * j + lrow;
#pragma unroll
                for (int i = 0; i < 9; i++) {
#pragma unroll
                    for (int r = 0; r < 4; r++) {
                        int lr = ((i < 5) ? 16 * i : 80 + 16 * (i - 5)) + quad * 4 + r;
                        float v = acc[i][j][r] + bias[j];
                        v = v > 0.f ? v : 0.f;
                        sm[lr * RP1 + col] = f2bf(v);
                    }
                }
            }
        }
        __syncthreads();
        // 144 rows x 4 segs of 128B = 576 row-segs; 512 threads -> 2 iterations (2nd partial)
#pragma unroll
        for (int it = 0; it < 2; it++) {
            int idx = it * 512 + t;
            if (idx < 576) {
                int row = idx >> 2, seg = idx & 3;
                int grow = half * 144 + row;
                if (m0 + grow < cnt) {
                    unsigned short* dst = mid + (size_t)(base + m0 + grow) * HH + n0 + seg * 64;
                    const unsigned short* src = sm + row * RP1 + seg * 64;
#pragma unroll
                    for (int k = 0; k < 8; k++)
                        *(uint4*)(dst + k * 8) = *(const uint4*)(src + k * 8);
                }
            }
        }
        __syncthreads();
    }
}

// ---- grouped GEMM 2: 160x128, BK=64, 2-slot dbuf (72 KB -> 2 blk/CU, ~416 blocks ALL resident) ----
// ybuf[slot] = gate * (mid @ w2[e] + b2[e]); 8 waves of 80x32; 5 chunks/thread (3 A dup-pad + 2 B)
__global__ __launch_bounds__(512, 4) void k_ffn2(
    const unsigned short* __restrict__ mid, const unsigned short* __restrict__ w2t,
    const float* __restrict__ b2, const int* __restrict__ ctl, const int* __restrict__ tiles,
    const float* __restrict__ gv, const int* __restrict__ rtok, unsigned short* __restrict__ ybuf) {
    int flat = blockIdx.x;
    int c8 = flat & 7, q = flat >> 3;
    int nt = q & 3, mt = (q >> 2) * 8 + c8;
    if (mt >= ctl[13]) return;
    int tv = tiles[mt];
    int e = tv >> 16, m0 = tv & 0xFFFF;
    int base = ctl[8 + e];
    int cnt = ctl[9 + e] - base;
    int n0 = nt * 128;

    __shared__ unsigned short sm[2 * SLOT2];   // 72 KB dbuf; epilogue repack (160 x RP2) aliases
    __shared__ float gts[160];

    int t = threadIdx.x;
    if (t < 160) {
        int r = m0 + t; if (r >= cnt) r = cnt - 1;
        gts[t] = gv[rtok[base + r]];
    }
    __syncthreads();

    const unsigned short* wB = w2t + (size_t)e * DD * HH;
    int idxA[3]; idxA[0] = t; idxA[1] = 512 + t; idxA[2] = (t < 256) ? (1024 + t) : (512 + t);
    const unsigned short* gA[3]; int lofA[3];
#pragma unroll
    for (int r = 0; r < 3; r++) {
        int row = idxA[r] >> 3, sch = idxA[r] & 7;
        int cg = (sch - row) & 7;
        int ra = m0 + row; if (ra >= cnt) ra = cnt - 1;
        gA[r] = mid + (size_t)(base + ra) * HH + cg * 8;
        lofA[r] = idxA[r] * 8;
    }
    const unsigned short* gB[2]; int lofB[2];
#pragma unroll
    for (int r = 0; r < 2; r++) {
        int idx = r * 512 + t;
        int row = idx >> 3, sch = idx & 7;
        int cg = (sch - row) & 7;
        gB[r] = wB + (size_t)(n0 + row) * HH + cg * 8;
        lofB[r] = ASZ2 + idx * 8;
    }

    int w = t >> 6, lane = t & 63;
    int wm = (w >> 2) * 80, wn = (w & 3) * 32;   // wave tile 80x32
    int lrow = lane & 15, quad = lane >> 4;

    floatx4 acc[5][2];
#pragma unroll
    for (int i = 0; i < 5; i++)
#pragma unroll
        for (int j = 0; j < 2; j++) acc[i][j] = (floatx4)0.f;

    // prologue: stage K-tile 0 (A then B)
#pragma unroll
    for (int r = 0; r < 3; r++) gld_lds16(gA[r], sm + lofA[r]);
#pragma unroll
    for (int r = 0; r < 2; r++) gld_lds16(gB[r], sm + lofB[r]);

    const int NK = HH / 64;   // 32
    for (int tt = 0; tt < NK; tt++) {
        const unsigned short* SA = sm + (tt & 1) * SLOT2;
        const unsigned short* SB = SA + ASZ2;
        unsigned short* sb = sm + ((tt + 1) & 1) * SLOT2;
        int k1 = (tt + 1) * 64;
        bool more = (tt + 1 < NK);

        if (more) {
#pragma unroll
            for (int r = 0; r < 3; r++) gld_lds16(gA[r] + k1, sb + lofA[r]);
            asm volatile("s_waitcnt vmcnt(3)" ::: "memory");   // tile tt's 5 chunks landed
        } else {
            asm volatile("s_waitcnt vmcnt(0)" ::: "memory");
        }
        __builtin_amdgcn_s_barrier();
        asm volatile("" ::: "memory");

        short8 af[5][2], bf[2][2];
#pragma unroll
        for (int i = 0; i < 5; i++)
#pragma unroll
            for (int ks = 0; ks < 2; ks++) {
                int row = wm + 16 * i + lrow;
                af[i][ks] = *(const short8*)&SA[row * 64 + (((ks << 2) + quad + row) & 7) * 8];
            }
#pragma unroll
        for (int j = 0; j < 2; j++)
#pragma unroll
            for (int ks = 0; ks < 2; ks++) {
                int row = wn + 16 * j + lrow;
                bf[j][ks] = *(const short8*)&SB[row * 64 + (((ks << 2) + quad + row) & 7) * 8];
            }
        if (more) { gld_lds16(gB[0] + k1, sb + lofB[0]); gld_lds16(gB[1] + k1, sb + lofB[1]); }
        __builtin_amdgcn_s_setprio(1);
#pragma unroll
        for (int i = 0; i < 5; i++)
#pragma unroll
            for (int j = 0; j < 2; j++)
#pragma unroll
                for (int ks = 0; ks < 2; ks++)
                    acc[i][j] = __builtin_amdgcn_mfma_f32_16x16x32_bf16(af[i][ks], bf[j][ks], acc[i][j], 0, 0, 0);
        __builtin_amdgcn_s_setprio(0);
        asm volatile("" ::: "memory");
        __builtin_amdgcn_s_barrier();
        asm volatile("" ::: "memory");
    }
    __syncthreads();

    // epilogue: bias + gate-scale -> repack (160 x RP2) -> coalesced stores
    float b2v[2];
#pragma unroll
    for (int j = 0; j < 2; j++) b2v[j] = b2[e * DD + n0 + wn + 16 * j + lrow];
#pragma unroll
    for (int j = 0; j < 2; j++) {
        int col = wn + 16 * j + lrow;
#pragma unroll
        for (int i = 0; i < 5; i++) {
#pragma unroll
            for (int r = 0; r < 4; r++) {
                int m = wm + 16 * i + quad * 4 + r;
                float v = (acc[i][j][r] + b2v[j]) * gts[m];
                sm[m * RP2 + col] = f2bf(v);
            }
        }
    }
    __syncthreads();
    {
        int row = t >> 1, half = t & 1;   // rows 0..159 x 2 segs of 128B (t < 320 active)
        if (row < 160 && m0 + row < cnt) {
            unsigned short* dst = ybuf + (size_t)(base + m0 + row) * DD + n0 + half * 64;
            const unsigned short* src = sm + row * RP2 + half * 64;
#pragma unroll
            for (int k = 0; k < 8; k++)
                *(uint4*)(dst + k * 8) = *(const uint4*)(src + k * 8);
        }
    }
}

// ---------------- combine (512 thr, 4 tokens/block): out[n] = ybuf[slot(n,0)] + ybuf[slot(n,1)] ----------------
__global__ __launch_bounds__(512) void k_combine(const unsigned short* __restrict__ ybuf,
                                                 const int* __restrict__ slotof,
                                                 float* __restrict__ out) {
    int n = blockIdx.x * 4 + (threadIdx.x >> 7);
    int c = (threadIdx.x & 127) * 4;
    int sA = slotof[2 * n], sB = slotof[2 * n + 1];
    ushort4 a = *(const ushort4*)(ybuf + (size_t)sA * DD + c);
    ushort4 b = *(const ushort4*)(ybuf + (size_t)sB * DD + c);
    float4 o;
    o.x = bf2f(a.x) + bf2f(b.x);
    o.y = bf2f(a.y) + bf2f(b.y);
    o.z = bf2f(a.z) + bf2f(b.z);
    o.w = bf2f(a.w) + bf2f(b.w);
    *(float4*)(out + (size_t)n * DD + c) = o;
}

extern "C" void kernel_launch(void* const* d_in, const int* in_sizes, int n_in,
                              void* d_out, int out_size, void* d_ws, size_t ws_size,
                              hipStream_t stream) {
    const float* h  = (const float*)d_in[0];
    const float* wg = (const float*)d_in[1];
    const float* w1 = (const float*)d_in[2];
    const float* b1 = (const float*)d_in[3];
    const float* w2 = (const float*)d_in[4];
    const float* b2 = (const float*)d_in[5];
    float* out = (float*)d_out;

    char* ws = (char*)d_ws;
    size_t off = 0;
    auto alloc = [&](size_t bytes) -> void* {
        void* p = ws + off;
        off += (bytes + 255) & ~(size_t)255;
        return p;
    };
    unsigned short* hb  = (unsigned short*)alloc((size_t)NT * DD * 2);        // dead after ffn1
    unsigned short* w1t = (unsigned short*)alloc((size_t)NE * HH * DD * 2);   // dead after ffn1
    unsigned short* w2t = (unsigned short*)alloc((size_t)NE * DD * HH * 2);
    int*   sel    = (int*)alloc((size_t)NT * 2 * 4);
    float* gv     = (float*)alloc((size_t)NT * 2 * 4);
    int*   ctl    = (int*)alloc(256);
    int*   tiles  = (int*)alloc(1024);
    int*   tiles2 = (int*)alloc(1024);
    int*   rtok   = (int*)alloc((size_t)NT * 2 * 4);
    int*   slotof = (int*)alloc((size_t)NT * 2 * 4);
    unsigned short* mid = (unsigned short*)alloc((size_t)NT * 2 * HH * 2);
    // ybuf [NT*2][DD] bf16 (16.7 MB) aliases hb+w1t (16.7 MB), both dead before ffn2 runs
    unsigned short* ybuf = (unsigned short*)ws;

    k_gate<<<dim3(NT / 8), 512, 0, stream>>>(h, wg, sel, gv, hb);
    k_scanT<<<dim3(1 + 1024), 1024, 0, stream>>>(sel, ctl, rtok, slotof, tiles, tiles2, w1, w1t, w2, w2t);
    k_ffn1<<<dim3(FFN1_GRID), 512, 0, stream>>>(hb, w1t, b1, ctl, tiles2, rtok, mid);
    k_ffn2<<<dim3(FFN2_GRID), 512, 0, stream>>>(mid, w2t, b2, ctl, tiles, gv, rtok, ybuf);
    k_combine<<<dim3(NT / 4), 512, 0, stream>>>(ybuf, slotof, out);
}